// Round 3
// baseline (10.283 us; speedup 1.0000x reference)
//
#include <hip/hip_runtime.h>

// MaskNeighborSampler — 4 rows per 64-lane wave, float4/int4 row loads.
//
// Wave w handles rows 4w..4w+3. Lane group g = lane>>4 owns row 4w+g:
//   each of the 16 lanes in the group loads float4/int4 -> one vector load
//   instruction fetches ALL 4 rows (64 lanes x 16B = 1KB, max coalescing).
//   count: per-lane popcount of 4 compares + 4-step shfl_xor reduce (width 16).
//   sampling: lane handles 2 consecutive samples of its own row; the sampled
//   element lives in lane (lane&48)+(col>>2), element col&3 -> 4 shfls + select.
//   u load and both outputs are coalesced float2 accesses.
//
// Output layout (single float32 buffer, tuple concatenated):
//   d_out[0 .. B*S)    = neighbors (ids < 2^24, exact in f32)
//   d_out[B*S .. 2BS)  = ts values

#define NSAMP 32

__device__ __forceinline__ float sel4(float x, float y, float z, float w, int e) {
  float lo = (e & 1) ? y : x;
  float hi = (e & 1) ? w : z;
  return (e & 2) ? hi : lo;
}

__global__ __launch_bounds__(256) void MaskNeighborSampler_kernel(
    const int* __restrict__ ids,
    const float* __restrict__ tss,
    const int4* __restrict__ adj4,
    const float4* __restrict__ tsi4,
    const float2* __restrict__ u2,
    float2* __restrict__ out_nbr2,
    float2* __restrict__ out_ts2,
    int B) {
  const int wave = (blockIdx.x * blockDim.x + threadIdx.x) >> 6;
  const int lane = threadIdx.x & 63;
  const int g    = lane >> 4;            // row within wave (0..3)
  const int k16  = lane & 15;
  int row = wave * 4 + g;
  if (wave * 4 >= B) return;
  if (row >= B) row = B - 1;             // B is a multiple of 4; belt-and-braces

  const int   id = ids[row];
  const float t  = tss[row];

  // one dwordx4 load per table covers all 4 rows of the wave
  const float4 ts4 = tsi4[(size_t)id * 16 + k16];
  const int4   ad4 = adj4[(size_t)id * 16 + k16];

  // valid-prefix count (strict f32 compare, exact integer sum)
  int cnt = (int)(ts4.x < t) + (int)(ts4.y < t) + (int)(ts4.z < t) + (int)(ts4.w < t);
  cnt += __shfl_xor(cnt, 1, 16);
  cnt += __shfl_xor(cnt, 2, 16);
  cnt += __shfl_xor(cnt, 4, 16);
  cnt += __shfl_xor(cnt, 8, 16);
  const int count = cnt;                 // uniform within the 16-lane group
  const int err   = count > 0 ? count : 1;
  const float errf = (float)err;

  // adj as float candidates for uniform select/shfl path (ids < 2^24: exact)
  const float a0 = (float)ad4.x, a1 = (float)ad4.y, a2 = (float)ad4.z, a3 = (float)ad4.w;

  // two consecutive samples per lane, same row as the lane's group
  const float2 uu = u2[(size_t)wave * 64 + lane];
  const int gbase = lane & 48;
  const int cmax  = err - 1;

  int c0 = (int)(uu.x * errf); if (c0 > cmax) c0 = cmax;   // IEEE mul+trunc as ref
  int c1 = (int)(uu.y * errf); if (c1 > cmax) c1 = cmax;
  const int s0 = gbase + (c0 >> 2), e0 = c0 & 3;
  const int s1 = gbase + (c1 >> 2), e1 = c1 & 3;

  // fetch candidates from the source lane, then select the element
  const float t0x = __shfl(ts4.x, s0, 64), t0y = __shfl(ts4.y, s0, 64);
  const float t0z = __shfl(ts4.z, s0, 64), t0w = __shfl(ts4.w, s0, 64);
  const float n0x = __shfl(a0, s0, 64),    n0y = __shfl(a1, s0, 64);
  const float n0z = __shfl(a2, s0, 64),    n0w = __shfl(a3, s0, 64);
  const float t1x = __shfl(ts4.x, s1, 64), t1y = __shfl(ts4.y, s1, 64);
  const float t1z = __shfl(ts4.z, s1, 64), t1w = __shfl(ts4.w, s1, 64);
  const float n1x = __shfl(a0, s1, 64),    n1y = __shfl(a1, s1, 64);
  const float n1z = __shfl(a2, s1, 64),    n1w = __shfl(a3, s1, 64);

  const bool valid = count > 0;
  float2 onbr, ots;
  onbr.x = valid ? sel4(n0x, n0y, n0z, n0w, e0) : 0.0f;
  onbr.y = valid ? sel4(n1x, n1y, n1z, n1w, e1) : 0.0f;
  ots.x  = valid ? sel4(t0x, t0y, t0z, t0w, e0) : 0.0f;
  ots.y  = valid ? sel4(t1x, t1y, t1z, t1w, e1) : 0.0f;

  out_nbr2[(size_t)wave * 64 + lane] = onbr;
  out_ts2 [(size_t)wave * 64 + lane] = ots;
}

extern "C" void kernel_launch(void* const* d_in, const int* in_sizes, int n_in,
                              void* d_out, int out_size, void* d_ws, size_t ws_size,
                              hipStream_t stream) {
  const int*   ids = (const int*)  d_in[0];
  const float* tss = (const float*)d_in[1];
  const int*   adj = (const int*)  d_in[2];
  const float* tsi = (const float*)d_in[3];
  const float* u   = (const float*)d_in[4];
  const int B = in_sizes[0];

  float* out_nbr = (float*)d_out;
  float* out_ts  = out_nbr + (size_t)B * NSAMP;

  const int waves   = (B + 3) / 4;                 // 4 rows per wave
  const int threads = 256;                         // 4 waves/block = 16 rows
  const int grid    = (waves * 64 + threads - 1) / threads;
  MaskNeighborSampler_kernel<<<grid, threads, 0, stream>>>(
      ids, tss, (const int4*)adj, (const float4*)tsi, (const float2*)u,
      (float2*)out_nbr, (float2*)out_ts, B);
}